// Round 6
// baseline (141.675 us; speedup 1.0000x reference)
//
#include <hip/hip_runtime.h>
#include <stdint.h>

#define BB 8
#define NN 2048
#define KK 32
#define FIN 256
#define FOUT 256
#define CC 512                 // 2*FOUT channels
#define MM (BB*NN)             // 16384 rows
#define RB 32                  // rows per gemm block
#define NBLK (MM/RB)           // 512 gemm blocks (= 2 per CU)
#define LDA 264                // padded LDS row stride (ushorts)

typedef __attribute__((ext_vector_type(8))) short short8;
typedef __attribute__((ext_vector_type(4))) float f32x4;

__device__ __forceinline__ unsigned short f2bf(float f) {
    union { float f; unsigned u; } v; v.f = f;
    unsigned u = v.u;
    return (unsigned short)((u + 0x7FFFu + ((u >> 16) & 1u)) >> 16);  // RNE
}
__device__ __forceinline__ float bf2f(unsigned short s) {
    union { unsigned u; float f; } v; v.u = ((unsigned)s) << 16;
    return v.f;
}

// ---------------- K1: W pack (blocks [0,128)) + x->bf16 conv (blocks [128,2176))
// Conv output xb feeds both the gather (268 MB instead of 536 MB of L3 reads)
// and the self-tile staging in k_gemm.
__global__ void k_prep(const float* __restrict__ Wx, const float* __restrict__ Wxb,
                       const float* __restrict__ Wn, const float* __restrict__ Wnb,
                       const float* __restrict__ x,
                       unsigned short* __restrict__ Wc, float* __restrict__ bc,
                       unsigned short* __restrict__ xb) {
    const int blk = blockIdx.x;
    const int tid = threadIdx.x;
    if (blk < 128) {            // weight pack + bias concat
        int gid = blk * 256 + tid;                  // 4 elems each
        int e0 = gid * 4;
        int o = e0 >> 8, k = e0 & 255;
        const float* src = (o < FOUT) ? (Wx + o * FIN + k) : (Wn + (o - FOUT) * FIN + k);
        float4 v = *(const float4*)src;
        ushort4 p; p.x = f2bf(v.x); p.y = f2bf(v.y); p.z = f2bf(v.z); p.w = f2bf(v.w);
        *(ushort4*)(Wc + e0) = p;
        if (gid < 128) {
            int c0 = gid * 4;
            float4 bv = (c0 < FOUT) ? *(const float4*)(Wxb + c0)
                                    : *(const float4*)(Wnb + c0 - FOUT);
            *(float4*)(bc + c0) = bv;
        }
    } else {                    // x fp32 -> bf16, 8 elems/thread
        size_t gid = (size_t)(blk - 128) * 256 + tid;
        size_t e0 = gid * 8;
        float4 v0 = *(const float4*)(x + e0);
        float4 v1 = *(const float4*)(x + e0 + 4);
        ushort4 p0, p1;
        p0.x = f2bf(v0.x); p0.y = f2bf(v0.y); p0.z = f2bf(v0.z); p0.w = f2bf(v0.w);
        p1.x = f2bf(v1.x); p1.y = f2bf(v1.y); p1.z = f2bf(v1.z); p1.w = f2bf(v1.w);
        *(ushort4*)(xb + e0)     = p0;
        *(ushort4*)(xb + e0 + 4) = p1;
    }
}

// ---------------- K2: self-stage (bf16 copy) + in-block bf16 neighbor gather-mean
//                  + dual MFMA GEMM + bias + row L2-norm + ReLU + bf16 h
//                  + BN channel partials.
__global__ __launch_bounds__(256, 2)
void k_gemm(const unsigned short* __restrict__ xb, const int* __restrict__ idx,
            const unsigned short* __restrict__ Wc,
            const float* __restrict__ bc,
            unsigned short* __restrict__ h,
            float* __restrict__ psum, float* __restrict__ psq) {
    __shared__ unsigned short As[2][RB * LDA];   // [0]=self rows, [1]=neighbor rows
    __shared__ float sqpart[4][RB];
    __shared__ float rnorm[RB];

    const int bid  = blockIdx.x;
    const int tid  = threadIdx.x;
    const int w    = tid >> 6;
    const int lane = tid & 63;
    const int quad = lane >> 4;
    const int l16  = lane & 15;
    const int b    = bid & 7;
    const int n0   = (bid >> 3) * RB;
    const unsigned short* xbat = xb + (size_t)b * NN * FIN;
    const size_t r0g = (size_t)b * NN + n0;      // global output row base

    {   // self tile: bf16 vec8 copy into padded LDS
        const uint4* gs = (const uint4*)(xbat + (size_t)n0 * FIN);
        #pragma unroll
        for (int i = 0; i < 4; ++i) {
            int e = tid + i * 256;               // vec8 idx 0..1023: row=e>>5, col8=e&31
            *(uint4*)&As[0][(e >> 5) * LDA + (e & 31) * 8] = gs[e];
        }
    }
    {   // neighbor gather-mean (bf16 reads): wave w -> local rows w*8..w*8+7
        #pragma unroll
        for (int rr = 0; rr < 8; ++rr) {
            int lr = w * 8 + rr;
            const int* ip = idx + (n0 + lr) * KK;      // wave-uniform -> s_load
            const unsigned short* xp = xbat + lane * 4;
            float a0 = 0.f, a1 = 0.f, a2 = 0.f, a3 = 0.f;
            #pragma unroll 8
            for (int k = 0; k < KK; ++k) {
                ushort4 v = *(const ushort4*)(xp + (size_t)ip[k] * FIN);
                a0 += bf2f(v.x); a1 += bf2f(v.y); a2 += bf2f(v.z); a3 += bf2f(v.w);
            }
            const float s = 1.0f / (float)KK;
            ushort4 o4; o4.x = f2bf(a0 * s); o4.y = f2bf(a1 * s);
            o4.z = f2bf(a2 * s); o4.w = f2bf(a3 * s);
            *(ushort4*)&As[1][lr * LDA + lane * 4] = o4;
        }
    }
    __syncthreads();

    const unsigned short* A = As[w >> 1];        // waves 0,1: self; 2,3: neighbor
    const int cb = w * 128;                      // wave's 128 output channels

    f32x4 acc[2][8];
    #pragma unroll
    for (int mt = 0; mt < 2; ++mt)
        #pragma unroll
        for (int nt = 0; nt < 8; ++nt) acc[mt][nt] = (f32x4){0.f, 0.f, 0.f, 0.f};

    const unsigned short* Bp = Wc + (size_t)(cb + l16) * FIN + quad * 8;  // B^T frag base
    const unsigned short* Ap = A + (size_t)l16 * LDA + quad * 8;

    #pragma unroll 2
    for (int k0 = 0; k0 < FIN; k0 += 32) {
        short8 a0 = *(const short8*)(Ap + k0);
        short8 a1 = *(const short8*)(Ap + 16 * LDA + k0);
        short8 bfr[8];
        #pragma unroll
        for (int nt = 0; nt < 8; ++nt)
            bfr[nt] = *(const short8*)(Bp + (size_t)nt * 16 * FIN + k0);
        #pragma unroll
        for (int nt = 0; nt < 8; ++nt) {
            acc[0][nt] = __builtin_amdgcn_mfma_f32_16x16x32_bf16(a0, bfr[nt], acc[0][nt], 0, 0, 0);
            acc[1][nt] = __builtin_amdgcn_mfma_f32_16x16x32_bf16(a1, bfr[nt], acc[1][nt], 0, 0, 0);
        }
    }

    // bias + per-row sum of squares (C/D layout: col=l16, row=quad*4+reg)
    float bcv[8];
    #pragma unroll
    for (int nt = 0; nt < 8; ++nt) bcv[nt] = bc[cb + nt * 16 + l16];

    float rsq[2][4] = {{0.f,0.f,0.f,0.f},{0.f,0.f,0.f,0.f}};
    #pragma unroll
    for (int mt = 0; mt < 2; ++mt)
        #pragma unroll
        for (int nt = 0; nt < 8; ++nt)
            #pragma unroll
            for (int r = 0; r < 4; ++r) {
                float v = acc[mt][nt][r] + bcv[nt];
                acc[mt][nt][r] = v;
                rsq[mt][r] += v * v;
            }
    #pragma unroll
    for (int off = 1; off < 16; off <<= 1)
        #pragma unroll
        for (int mt = 0; mt < 2; ++mt)
            #pragma unroll
            for (int r = 0; r < 4; ++r)
                rsq[mt][r] += __shfl_xor(rsq[mt][r], off, 64);
    if (l16 == 0) {
        #pragma unroll
        for (int mt = 0; mt < 2; ++mt)
            #pragma unroll
            for (int r = 0; r < 4; ++r)
                sqpart[w][mt * 16 + quad * 4 + r] = rsq[mt][r];
    }
    __syncthreads();
    if (tid < RB) {
        float tot = sqpart[0][tid] + sqpart[1][tid] + sqpart[2][tid] + sqpart[3][tid];
        rnorm[tid] = 1.0f / fmaxf(sqrtf(tot), 1e-12f);
    }
    __syncthreads();

    // normalize + relu + h store (bf16) + channel partials
    float csum[8] = {0.f,0.f,0.f,0.f,0.f,0.f,0.f,0.f};
    float csq [8] = {0.f,0.f,0.f,0.f,0.f,0.f,0.f,0.f};
    #pragma unroll
    for (int mt = 0; mt < 2; ++mt) {
        #pragma unroll
        for (int r = 0; r < 4; ++r) {
            int row = mt * 16 + quad * 4 + r;
            float rn = rnorm[row];
            unsigned short* hp = h + (r0g + row) * CC + cb + l16;
            #pragma unroll
            for (int nt = 0; nt < 8; ++nt) {
                float v = fmaxf(acc[mt][nt][r] * rn, 0.0f);
                hp[nt * 16] = f2bf(v);
                csum[nt] += v;
                csq [nt] += v * v;
            }
        }
    }
    #pragma unroll
    for (int off = 16; off < 64; off <<= 1)
        #pragma unroll
        for (int nt = 0; nt < 8; ++nt) {
            csum[nt] += __shfl_xor(csum[nt], off, 64);
            csq [nt] += __shfl_xor(csq [nt], off, 64);
        }
    if (quad == 0) {
        #pragma unroll
        for (int nt = 0; nt < 8; ++nt) {
            int c = cb + nt * 16 + l16;
            psum[(size_t)c * NBLK + bid] = csum[nt];
            psq [(size_t)c * NBLK + bid] = csq [nt];
        }
    }
}

// ---------------- K3: reduce BN partials -> per-channel scale/shift
__global__ void k_stats(const float* __restrict__ psum, const float* __restrict__ psq,
                        const float* __restrict__ gamma, const float* __restrict__ beta,
                        float* __restrict__ ss) {
    __shared__ float ps[4], pq[4];
    int c = blockIdx.x, t = threadIdx.x;
    float s = psum[(size_t)c * NBLK + t] + psum[(size_t)c * NBLK + 256 + t];
    float q = psq [(size_t)c * NBLK + t] + psq [(size_t)c * NBLK + 256 + t];
    #pragma unroll
    for (int off = 32; off; off >>= 1) { s += __shfl_xor(s, off, 64); q += __shfl_xor(q, off, 64); }
    int w = t >> 6, lane = t & 63;
    if (lane == 0) { ps[w] = s; pq[w] = q; }
    __syncthreads();
    if (t == 0) {
        float S = ps[0] + ps[1] + ps[2] + ps[3];
        float Q = pq[0] + pq[1] + pq[2] + pq[3];
        const float inv = 1.0f / (float)MM;
        float mu  = S * inv;
        float var = fmaxf(Q * inv - mu * mu, 0.0f);
        float sc  = gamma[c] * rsqrtf(var + 1e-5f);
        ss[c]      = sc;
        ss[CC + c] = beta[c] - mu * sc;
    }
}

// ---------------- K4: BN apply, bf16 h -> fp32 out, 8 elems/thread
__global__ void k_apply(const unsigned short* __restrict__ h,
                        const float* __restrict__ ss,
                        float* __restrict__ out) {
    int gid = blockIdx.x * 256 + threadIdx.x;   // 8 elems/thread
    int c0 = (gid * 8) & (CC - 1);
    uint4 hv = ((const uint4*)h)[gid];          // 8 bf16
    const unsigned short* hs = (const unsigned short*)&hv;
    float4 sc0 = *(const float4*)(ss + c0);
    float4 sc1 = *(const float4*)(ss + c0 + 4);
    float4 sh0 = *(const float4*)(ss + CC + c0);
    float4 sh1 = *(const float4*)(ss + CC + c0 + 4);
    float4 o0, o1;
    o0.x = bf2f(hs[0]) * sc0.x + sh0.x;
    o0.y = bf2f(hs[1]) * sc0.y + sh0.y;
    o0.z = bf2f(hs[2]) * sc0.z + sh0.z;
    o0.w = bf2f(hs[3]) * sc0.w + sh0.w;
    o1.x = bf2f(hs[4]) * sc1.x + sh1.x;
    o1.y = bf2f(hs[5]) * sc1.y + sh1.y;
    o1.z = bf2f(hs[6]) * sc1.z + sh1.z;
    o1.w = bf2f(hs[7]) * sc1.w + sh1.w;
    ((float4*)out)[gid * 2]     = o0;
    ((float4*)out)[gid * 2 + 1] = o1;
}

extern "C" void kernel_launch(void* const* d_in, const int* in_sizes, int n_in,
                              void* d_out, int out_size, void* d_ws, size_t ws_size,
                              hipStream_t stream) {
    const float* x     = (const float*)d_in[0];
    const int*   idx   = (const int*)  d_in[1];
    const float* Wx_w  = (const float*)d_in[2];
    const float* Wx_b  = (const float*)d_in[3];
    const float* Wn_w  = (const float*)d_in[4];
    const float* Wn_b  = (const float*)d_in[5];
    const float* gamma = (const float*)d_in[6];
    const float* beta  = (const float*)d_in[7];
    float* out = (float*)d_out;

    char* p = (char*)d_ws;
    unsigned short* xb = (unsigned short*)p; p += (size_t)MM * FIN * 2;   // 8.4 MB
    unsigned short* Wc = (unsigned short*)p; p += (size_t)CC * FIN * 2;   // 256 KB
    float* bc          = (float*)p;          p += (size_t)CC * 4;         // 2 KB
    unsigned short* h  = (unsigned short*)p; p += (size_t)MM * CC * 2;    // 16.8 MB
    float* psum        = (float*)p;          p += (size_t)CC * NBLK * 4;  // 1 MB
    float* psq         = (float*)p;          p += (size_t)CC * NBLK * 4;  // 1 MB
    float* ss          = (float*)p;          p += (size_t)2 * CC * 4;     // 4 KB

    hipLaunchKernelGGL(k_prep,  dim3(2176), dim3(256), 0, stream,
                       Wx_w, Wx_b, Wn_w, Wn_b, x, Wc, bc, xb);
    hipLaunchKernelGGL(k_gemm,  dim3(NBLK), dim3(256), 0, stream, xb, idx, Wc, bc, h, psum, psq);
    hipLaunchKernelGGL(k_stats, dim3(CC),   dim3(256), 0, stream, psum, psq, gamma, beta, ss);
    hipLaunchKernelGGL(k_apply, dim3(4096), dim3(256), 0, stream, h, ss, out);
}

// Round 7
// 130.405 us; speedup vs baseline: 1.0864x; 1.0864x over previous
//
#include <hip/hip_runtime.h>
#include <stdint.h>

#define BB 8
#define NN 2048
#define KK 32
#define FIN 256
#define FOUT 256
#define CC 512                 // 2*FOUT channels
#define MM (BB*NN)             // 16384 rows
#define RB 32                  // rows per gemm block
#define NBLK (MM/RB)           // 512 gemm blocks (= 2 per CU)
#define LDA 264                // padded LDS row stride (ushorts)

typedef __attribute__((ext_vector_type(8))) short short8;
typedef __attribute__((ext_vector_type(4))) float f32x4;

__device__ __forceinline__ unsigned short f2bf(float f) {
    union { float f; unsigned u; } v; v.f = f;
    unsigned u = v.u;
    return (unsigned short)((u + 0x7FFFu + ((u >> 16) & 1u)) >> 16);  // RNE
}
__device__ __forceinline__ float bf2f(unsigned short s) {
    union { unsigned u; float f; } v; v.u = ((unsigned)s) << 16;
    return v.f;
}

// ---------------- K1: W pack (blocks [0,128)) + x->bf16 conv (blocks [128,2176))
__global__ void k_prep(const float* __restrict__ Wx, const float* __restrict__ Wxb,
                       const float* __restrict__ Wn, const float* __restrict__ Wnb,
                       const float* __restrict__ x,
                       unsigned short* __restrict__ Wc, float* __restrict__ bc,
                       unsigned short* __restrict__ xb) {
    const int blk = blockIdx.x;
    const int tid = threadIdx.x;
    if (blk < 128) {            // weight pack + bias concat
        int gid = blk * 256 + tid;                  // 4 elems each
        int e0 = gid * 4;
        int o = e0 >> 8, k = e0 & 255;
        const float* src = (o < FOUT) ? (Wx + o * FIN + k) : (Wn + (o - FOUT) * FIN + k);
        float4 v = *(const float4*)src;
        ushort4 p; p.x = f2bf(v.x); p.y = f2bf(v.y); p.z = f2bf(v.z); p.w = f2bf(v.w);
        *(ushort4*)(Wc + e0) = p;
        if (gid < 128) {
            int c0 = gid * 4;
            float4 bv = (c0 < FOUT) ? *(const float4*)(Wxb + c0)
                                    : *(const float4*)(Wnb + c0 - FOUT);
            *(float4*)(bc + c0) = bv;
        }
    } else {                    // x fp32 -> bf16, 8 elems/thread
        size_t gid = (size_t)(blk - 128) * 256 + tid;
        size_t e0 = gid * 8;
        float4 v0 = *(const float4*)(x + e0);
        float4 v1 = *(const float4*)(x + e0 + 4);
        ushort4 p0, p1;
        p0.x = f2bf(v0.x); p0.y = f2bf(v0.y); p0.z = f2bf(v0.z); p0.w = f2bf(v0.w);
        p1.x = f2bf(v1.x); p1.y = f2bf(v1.y); p1.z = f2bf(v1.z); p1.w = f2bf(v1.w);
        *(ushort4*)(xb + e0)     = p0;
        *(ushort4*)(xb + e0 + 4) = p1;
    }
}

// ---------------- K2: 512 threads (8 waves): self-stage + wide gather-mean
//                  + dual MFMA GEMM + bias + row L2-norm + ReLU + bf16 h
//                  + BN channel partials.
// Gather concurrency: 16 waves/CU x ushort8 loads (2 neighbors per wave issue).
__global__ __launch_bounds__(512, 4)
void k_gemm(const unsigned short* __restrict__ xb, const int* __restrict__ idx,
            const unsigned short* __restrict__ Wc,
            const float* __restrict__ bc,
            unsigned short* __restrict__ h,
            float* __restrict__ psum, float* __restrict__ psq) {
    __shared__ unsigned short As[2][RB * LDA];   // [0]=self rows, [1]=neighbor rows
    __shared__ float sqpart[8][RB];
    __shared__ float rnorm[RB];

    const int bid  = blockIdx.x;
    const int tid  = threadIdx.x;
    const int w    = tid >> 6;          // 0..7
    const int lane = tid & 63;
    const int quad = lane >> 4;
    const int l16  = lane & 15;
    const int p    = lane >> 5;         // neighbor parity
    const int l32  = lane & 31;         // 8-channel group
    const int b    = bid & 7;
    const int n0   = (bid >> 3) * RB;
    const unsigned short* xbat = xb + (size_t)b * NN * FIN;
    const size_t r0g = (size_t)b * NN + n0;      // global output row base

    {   // self tile: 32 rows x 256 ch bf16 = 1024 uint4; 512 thr x 2
        const uint4* gs = (const uint4*)(xbat + (size_t)n0 * FIN);
        #pragma unroll
        for (int i = 0; i < 2; ++i) {
            int e = tid + i * 512;               // row=e>>5, col8=e&31
            *(uint4*)&As[0][(e >> 5) * LDA + (e & 31) * 8] = gs[e];
        }
    }
    {   // gather-mean: wave w -> local rows w*4..w*4+3; 2 neighbors per issue
        #pragma unroll
        for (int rr = 0; rr < 4; ++rr) {
            int lr = (w << 2) + rr;
            const int* ip = idx + (n0 + lr) * KK;      // wave-uniform
            const unsigned short* xp = xbat + l32 * 8;
            float ac[8] = {0.f,0.f,0.f,0.f,0.f,0.f,0.f,0.f};
            #pragma unroll 8
            for (int k = 0; k < 16; ++k) {
                int j = ip[(k << 1) | p];
                uint4 v = *(const uint4*)(xp + (size_t)j * FIN);
                const unsigned short* hv = (const unsigned short*)&v;
                #pragma unroll
                for (int c = 0; c < 8; ++c) ac[c] += bf2f(hv[c]);
            }
            #pragma unroll
            for (int c = 0; c < 8; ++c) ac[c] += __shfl_xor(ac[c], 32, 64);
            if (p == 0) {
                const float s = 1.0f / (float)KK;
                unsigned short o8[8];
                #pragma unroll
                for (int c = 0; c < 8; ++c) o8[c] = f2bf(ac[c] * s);
                *(uint4*)&As[1][lr * LDA + l32 * 8] = *(const uint4*)o8;
            }
        }
    }
    __syncthreads();

    const int half = w >> 2;                     // 0: self, 1: neighbor
    const unsigned short* A = As[half];
    const int cbg = half * 256 + (w & 3) * 64;   // wave's 64 output channels

    f32x4 acc[2][4];
    #pragma unroll
    for (int mt = 0; mt < 2; ++mt)
        #pragma unroll
        for (int nt = 0; nt < 4; ++nt) acc[mt][nt] = (f32x4){0.f, 0.f, 0.f, 0.f};

    const unsigned short* Bp = Wc + (size_t)(cbg + l16) * FIN + quad * 8;  // B^T frag base
    const unsigned short* Ap = A + (size_t)l16 * LDA + quad * 8;

    #pragma unroll 2
    for (int k0 = 0; k0 < FIN; k0 += 32) {
        short8 a0 = *(const short8*)(Ap + k0);
        short8 a1 = *(const short8*)(Ap + 16 * LDA + k0);
        short8 bfr[4];
        #pragma unroll
        for (int nt = 0; nt < 4; ++nt)
            bfr[nt] = *(const short8*)(Bp + (size_t)nt * 16 * FIN + k0);
        #pragma unroll
        for (int nt = 0; nt < 4; ++nt) {
            acc[0][nt] = __builtin_amdgcn_mfma_f32_16x16x32_bf16(a0, bfr[nt], acc[0][nt], 0, 0, 0);
            acc[1][nt] = __builtin_amdgcn_mfma_f32_16x16x32_bf16(a1, bfr[nt], acc[1][nt], 0, 0, 0);
        }
    }

    // bias + per-row sum of squares (C/D layout: col=l16, row=quad*4+reg)
    float bcv[4];
    #pragma unroll
    for (int nt = 0; nt < 4; ++nt) bcv[nt] = bc[cbg + nt * 16 + l16];

    float rsq[2][4] = {{0.f,0.f,0.f,0.f},{0.f,0.f,0.f,0.f}};
    #pragma unroll
    for (int mt = 0; mt < 2; ++mt)
        #pragma unroll
        for (int nt = 0; nt < 4; ++nt)
            #pragma unroll
            for (int r = 0; r < 4; ++r) {
                float v = acc[mt][nt][r] + bcv[nt];
                acc[mt][nt][r] = v;
                rsq[mt][r] += v * v;
            }
    #pragma unroll
    for (int off = 1; off < 16; off <<= 1)
        #pragma unroll
        for (int mt = 0; mt < 2; ++mt)
            #pragma unroll
            for (int r = 0; r < 4; ++r)
                rsq[mt][r] += __shfl_xor(rsq[mt][r], off, 64);
    if (l16 == 0) {
        #pragma unroll
        for (int mt = 0; mt < 2; ++mt)
            #pragma unroll
            for (int r = 0; r < 4; ++r)
                sqpart[w][mt * 16 + quad * 4 + r] = rsq[mt][r];
    }
    __syncthreads();
    if (tid < RB) {
        float tot = 0.f;
        #pragma unroll
        for (int i = 0; i < 8; ++i) tot += sqpart[i][tid];
        rnorm[tid] = 1.0f / fmaxf(sqrtf(tot), 1e-12f);
    }
    __syncthreads();

    // normalize + relu + h store (bf16) + channel partials
    float csum[4] = {0.f,0.f,0.f,0.f};
    float csq [4] = {0.f,0.f,0.f,0.f};
    #pragma unroll
    for (int mt = 0; mt < 2; ++mt) {
        #pragma unroll
        for (int r = 0; r < 4; ++r) {
            int row = mt * 16 + quad * 4 + r;
            float rn = rnorm[row];
            unsigned short* hp = h + (r0g + row) * CC + cbg + l16;
            #pragma unroll
            for (int nt = 0; nt < 4; ++nt) {
                float v = fmaxf(acc[mt][nt][r] * rn, 0.0f);
                hp[nt * 16] = f2bf(v);
                csum[nt] += v;
                csq [nt] += v * v;
            }
        }
    }
    #pragma unroll
    for (int off = 16; off < 64; off <<= 1)
        #pragma unroll
        for (int nt = 0; nt < 4; ++nt) {
            csum[nt] += __shfl_xor(csum[nt], off, 64);
            csq [nt] += __shfl_xor(csq [nt], off, 64);
        }
    if (quad == 0) {
        #pragma unroll
        for (int nt = 0; nt < 4; ++nt) {
            int c = cbg + nt * 16 + l16;
            psum[(size_t)c * NBLK + bid] = csum[nt];
            psq [(size_t)c * NBLK + bid] = csq [nt];
        }
    }
}

// ---------------- K3: reduce BN partials -> per-channel scale/shift
__global__ void k_stats(const float* __restrict__ psum, const float* __restrict__ psq,
                        const float* __restrict__ gamma, const float* __restrict__ beta,
                        float* __restrict__ ss) {
    __shared__ float ps[4], pq[4];
    int c = blockIdx.x, t = threadIdx.x;
    float s = psum[(size_t)c * NBLK + t] + psum[(size_t)c * NBLK + 256 + t];
    float q = psq [(size_t)c * NBLK + t] + psq [(size_t)c * NBLK + 256 + t];
    #pragma unroll
    for (int off = 32; off; off >>= 1) { s += __shfl_xor(s, off, 64); q += __shfl_xor(q, off, 64); }
    int w = t >> 6, lane = t & 63;
    if (lane == 0) { ps[w] = s; pq[w] = q; }
    __syncthreads();
    if (t == 0) {
        float S = ps[0] + ps[1] + ps[2] + ps[3];
        float Q = pq[0] + pq[1] + pq[2] + pq[3];
        const float inv = 1.0f / (float)MM;
        float mu  = S * inv;
        float var = fmaxf(Q * inv - mu * mu, 0.0f);
        float sc  = gamma[c] * rsqrtf(var + 1e-5f);
        ss[c]      = sc;
        ss[CC + c] = beta[c] - mu * sc;
    }
}

// ---------------- K4: BN apply, bf16 h -> fp32 out, 8 elems/thread
__global__ void k_apply(const unsigned short* __restrict__ h,
                        const float* __restrict__ ss,
                        float* __restrict__ out) {
    int gid = blockIdx.x * 256 + threadIdx.x;   // 8 elems/thread
    int c0 = (gid * 8) & (CC - 1);
    uint4 hv = ((const uint4*)h)[gid];          // 8 bf16
    const unsigned short* hs = (const unsigned short*)&hv;
    float4 sc0 = *(const float4*)(ss + c0);
    float4 sc1 = *(const float4*)(ss + c0 + 4);
    float4 sh0 = *(const float4*)(ss + CC + c0);
    float4 sh1 = *(const float4*)(ss + CC + c0 + 4);
    float4 o0, o1;
    o0.x = bf2f(hs[0]) * sc0.x + sh0.x;
    o0.y = bf2f(hs[1]) * sc0.y + sh0.y;
    o0.z = bf2f(hs[2]) * sc0.z + sh0.z;
    o0.w = bf2f(hs[3]) * sc0.w + sh0.w;
    o1.x = bf2f(hs[4]) * sc1.x + sh1.x;
    o1.y = bf2f(hs[5]) * sc1.y + sh1.y;
    o1.z = bf2f(hs[6]) * sc1.z + sh1.z;
    o1.w = bf2f(hs[7]) * sc1.w + sh1.w;
    ((float4*)out)[gid * 2]     = o0;
    ((float4*)out)[gid * 2 + 1] = o1;
}

extern "C" void kernel_launch(void* const* d_in, const int* in_sizes, int n_in,
                              void* d_out, int out_size, void* d_ws, size_t ws_size,
                              hipStream_t stream) {
    const float* x     = (const float*)d_in[0];
    const int*   idx   = (const int*)  d_in[1];
    const float* Wx_w  = (const float*)d_in[2];
    const float* Wx_b  = (const float*)d_in[3];
    const float* Wn_w  = (const float*)d_in[4];
    const float* Wn_b  = (const float*)d_in[5];
    const float* gamma = (const float*)d_in[6];
    const float* beta  = (const float*)d_in[7];
    float* out = (float*)d_out;

    char* p = (char*)d_ws;
    unsigned short* xb = (unsigned short*)p; p += (size_t)MM * FIN * 2;   // 8.4 MB
    unsigned short* Wc = (unsigned short*)p; p += (size_t)CC * FIN * 2;   // 256 KB
    float* bc          = (float*)p;          p += (size_t)CC * 4;         // 2 KB
    unsigned short* h  = (unsigned short*)p; p += (size_t)MM * CC * 2;    // 16.8 MB
    float* psum        = (float*)p;          p += (size_t)CC * NBLK * 4;  // 1 MB
    float* psq         = (float*)p;          p += (size_t)CC * NBLK * 4;  // 1 MB
    float* ss          = (float*)p;          p += (size_t)2 * CC * 4;     // 4 KB

    hipLaunchKernelGGL(k_prep,  dim3(2176), dim3(256), 0, stream,
                       Wx_w, Wx_b, Wn_w, Wn_b, x, Wc, bc, xb);
    hipLaunchKernelGGL(k_gemm,  dim3(NBLK), dim3(512), 0, stream, xb, idx, Wc, bc, h, psum, psq);
    hipLaunchKernelGGL(k_stats, dim3(CC),   dim3(256), 0, stream, psum, psq, gamma, beta, ss);
    hipLaunchKernelGGL(k_apply, dim3(4096), dim3(256), 0, stream, h, ss, out);
}